// Round 2
// baseline (171.613 us; speedup 1.0000x reference)
//
#include <hip/hip_runtime.h>
#include <math.h>

// B,H,W,C = 4,384,384,48; KERNEL=3 -> R=Cc=128 outputs per image dim.
// TF-faithful flat view: output F=((b*128+r)*128+cc)*48+g consumes 9
// contiguous floats at row (b*384+3r+kr), offset cc*144+(g&15)*9, kr=g>>4.
// Block = (b, r, kr, cc-octet): source region = 2304 contiguous floats.
//
// Redistribution is WAVE-LOCAL: wave w (i = tid>>4 in [4w,4w+4)) consumes
// exactly floats [576w, 576w+576) of the region — the same 2304 B it can
// stage itself with perfectly-coalesced 16 B/lane loads. So no
// __syncthreads(): each wave stages its own quarter and orders its
// ds_write -> ds_read with one s_waitcnt lgkmcnt(0) (intra-wave LDS
// shuffle idiom). Waves stream independently; no barrier drain.
#define ROW_STRIDE 18432
#define EPS 1e-4f

static __device__ __forceinline__ float rcp_f(float a) {
    return __builtin_amdgcn_rcpf(a);      // v_rcp_f32, 1 ulp
}

__global__ __launch_bounds__(256) void fuzzy_pool_kernel(
        const float* __restrict__ x, float* __restrict__ out) {
    __shared__ float s[2304];             // 9216 B staged input

    const int tid = threadIdx.x;
    const int bid = blockIdx.x;           // ((b*128+r)*3 + kr)*8 + c8
    const int c8 = bid & 7;
    const int t1 = bid >> 3;
    const int kr = t1 % 3;                // scalar magic-mul
    const int t2 = t1 / 3;
    const int r  = t2 & 127;
    const int b  = t2 >> 7;

    const float* __restrict__ src =
        x + ((size_t)(b * 384 + 3 * r + kr) * ROW_STRIDE + c8 * 2304);

    // ---- wave-local global -> LDS staging: 16B/lane coalesced ----
    const int wid  = tid >> 6;            // wave 0..3
    const int lane = tid & 63;
    const int wb   = wid * 144;           // wave's float4 base (576 floats)
    const float4* __restrict__ s4 = (const float4*)src;
    float4* l4 = (float4*)s;
    l4[wb + lane]      = s4[wb + lane];
    l4[wb + 64 + lane] = s4[wb + 64 + lane];
    if (lane < 16) l4[wb + 128 + lane] = s4[wb + 128 + lane];
    // Intra-wave ordering only: ds_writes complete -> visible to all lanes.
    asm volatile("s_waitcnt lgkmcnt(0)" ::: "memory");
    __builtin_amdgcn_sched_barrier(0);

    // thread (i = cc offset 0..15, j = g' 0..15)
    const int i = tid >> 4;
    const int j = tid & 15;
    const float* __restrict__ vp = s + (i * 144 + j * 9);  // 36B lane stride:
                                                           // 2-way banks, free
    float v[9];
#pragma unroll
    for (int t = 0; t < 9; ++t) v[t] = vp[t];

    const float R3 = 1.0f/3.0f, R5 = 0.2f, R7 = 1.0f/7.0f, R9 = 1.0f/9.0f;
    const float NC = -0.5f * 1.44269504088896340736f;   // -0.5*log2(e)

    // ---- membership(x): nested sums ----
    const float s3 = v[3] + v[4] + v[5];
    const float s5 = s3 + v[2] + v[6];
    const float s7 = s5 + v[1] + v[7];
    const float s9 = s7 + v[0] + v[8];
    const float m3 = s3 * R3, m5 = s5 * R5, m7 = s7 * R7, m9 = s9 * R9;

    float kmm[5];
    kmm[0] = m7; kmm[1] = m5; kmm[2] = m3; kmm[3] = v[4]; kmm[4] = m9;

    const float v_avg = (m7 + m5 + m3 + v[4] + m9) * R5;

    // ---- omega = |x - v_avg|; var = membership(omega) + eps ----
    float w[9];
#pragma unroll
    for (int t = 0; t < 9; ++t) w[t] = fabsf(v[t] - v_avg);

    const float t3 = w[3] + w[4] + w[5];
    const float t5 = t3 + w[2] + w[6];
    const float t7 = t5 + w[1] + w[7];
    const float t9 = t7 + w[0] + w[8];
    const float var4 = t9 * R9 + EPS;        // var[...,4] (m_only_var probe)

    float c[5];                               // c_j = -0.5*log2e / var_j
    c[0] = NC * rcp_f(t7 * R7 + EPS);
    c[1] = NC * rcp_f(t5 * R5 + EPS);
    c[2] = NC * rcp_f(t3 * R3 + EPS);
    c[3] = NC * rcp_f(w[4] + EPS);
    c[4] = NC * rcp_f(var4);

    // ---- pi[jj][t] = 2^(c_jj * d^2); sum over jj all t, max over jj t!=4 ----
    // Exact: pi[3][4] = 1.0 bit-exactly; all pi <= 1 so max_pi[4] = 1.0 and
    // t=4 drops out of the thresh min-tree.
    float sum_pi[9], max_pi[9];
#pragma unroll
    for (int t = 0; t < 9; ++t) { sum_pi[t] = 0.f; max_pi[t] = 0.f; }

#pragma unroll
    for (int jj = 0; jj < 5; ++jj) {
        const float k  = kmm[jj];
        const float cj = c[jj];
#pragma unroll
        for (int t = 0; t < 9; ++t) {
            if (jj == 3 && t == 4) {          // d = v[4]-v[4] = +-0 exactly
                sum_pi[4] += 1.0f;            // same summation slot/order
                continue;
            }
            const float d  = v[t] - k;
            const float pi = __builtin_amdgcn_exp2f(cj * d * d); // v_exp_f32
            sum_pi[t] += pi;
            if (t != 4) max_pi[t] = fmaxf(max_pi[t], pi);
        }
    }

    float thresh = fminf(fminf(max_pi[0], max_pi[1]), max_pi[2]);
    thresh = fminf(thresh, max_pi[3]);
    thresh = fminf(fminf(thresh, max_pi[5]), max_pi[6]);
    thresh = fminf(fminf(thresh, max_pi[7]), max_pi[8]);

    // any_t(sum_pi[t]*0.2 > thresh)  <=>  max_t(sum_pi)*0.2 > thresh
    // (x*0.2 rounding is monotone => exact equivalence)
    float ms = fmaxf(fmaxf(sum_pi[0], sum_pi[1]), sum_pi[2]);
    ms = fmaxf(fmaxf(ms, sum_pi[3]), sum_pi[4]);
    ms = fmaxf(fmaxf(ms, sum_pi[5]), sum_pi[6]);
    ms = fmaxf(fmaxf(ms, sum_pi[7]), sum_pi[8]);
    const bool m_mem = (ms * R5) > thresh;

    // weighted-average denoising; the 0.2 factor cancels in the ratio
    float sn = 0.f, sd = 0.f;
#pragma unroll
    for (int t = 0; t < 9; ++t) { sn += sum_pi[t] * v[t]; sd += sum_pi[t]; }
    const float denoised = sn * rcp_f(sd);

    const float res = m_mem ? m9 : ((var4 < EPS) ? v_avg : denoised);

    const int cc = c8 * 16 + i;
    const int g  = kr * 16 + j;
    out[((size_t)((b * 128 + r) * 128 + cc)) * 48 + g] = res;
}

extern "C" void kernel_launch(void* const* d_in, const int* in_sizes, int n_in,
                              void* d_out, int out_size, void* d_ws, size_t ws_size,
                              hipStream_t stream) {
    (void)in_sizes; (void)n_in; (void)d_ws; (void)ws_size; (void)out_size;
    const float* x = (const float*)d_in[0];
    float* out = (float*)d_out;
    const int blocks = 4 * 128 * 3 * 8;   // (b, r, kr, cc-octet) = 12288
    fuzzy_pool_kernel<<<blocks, 256, 0, stream>>>(x, out);
}

// Round 3
// 163.983 us; speedup vs baseline: 1.0465x; 1.0465x over previous
//
#include <hip/hip_runtime.h>
#include <math.h>

// B,H,W,C = 4,384,384,48; KERNEL=3 -> R=Cc=128 outputs per image dim.
// TF-faithful flat view: output F=((b*128+r)*128+cc)*48+g consumes 9
// contiguous floats at row (b*384+3r+kr), offset cc*144+(g&15)*9, kr=g>>4.
// Block = (b, r, kr, cc-octet): source region = 2304 contiguous floats.
//
// v3: 2 outputs/thread packed as float2 -> v_pk_{add,mul,fma}_f32 halves
// VALU issue (the kernel is compute/memory balanced; rounds 1-2 showed the
// memory path is already optimal). Pair (j, j+1) of the SAME region:
// identical LDS layout/staging, reads fuse to ds_read2_b32 (dword offsets
// t, t+9), results are adjacent -> one 8B dwordx2 store. All ops are
// elementwise-IEEE-identical in identical order -> bit-identical output.
#define ROW_STRIDE 18432
#define EPS 1e-4f

typedef float f2 __attribute__((ext_vector_type(2)));

static __device__ __forceinline__ float rcp_f(float a) {
    return __builtin_amdgcn_rcpf(a);      // v_rcp_f32, 1 ulp
}
static __device__ __forceinline__ f2 exp2_2(f2 a) {
    return (f2){__builtin_amdgcn_exp2f(a.x), __builtin_amdgcn_exp2f(a.y)};
}
static __device__ __forceinline__ f2 abs2(f2 a) {
    return (f2){fabsf(a.x), fabsf(a.y)};
}
static __device__ __forceinline__ f2 max2(f2 a, f2 b) {
    return (f2){fmaxf(a.x, b.x), fmaxf(a.y, b.y)};
}
static __device__ __forceinline__ f2 min2(f2 a, f2 b) {
    return (f2){fminf(a.x, b.x), fminf(a.y, b.y)};
}

__global__ __launch_bounds__(128) void fuzzy_pool_kernel(
        const float* __restrict__ x, float* __restrict__ out) {
    __shared__ float s[2304];             // 9216 B staged input

    const int tid = threadIdx.x;
    const int bid = blockIdx.x;           // ((b*128+r)*3 + kr)*8 + c8
    const int c8 = bid & 7;
    const int t1 = bid >> 3;
    const int kr = t1 % 3;                // scalar magic-mul
    const int t2 = t1 / 3;
    const int r  = t2 & 127;
    const int b  = t2 >> 7;

    const float* __restrict__ src =
        x + ((size_t)(b * 384 + 3 * r + kr) * ROW_STRIDE + c8 * 2304);

    // ---- coalesced global -> LDS staging: 576 float4, 16B/lane ----
    const float4* __restrict__ s4 = (const float4*)src;
    float4* l4 = (float4*)s;
    l4[tid]       = s4[tid];
    l4[tid + 128] = s4[tid + 128];
    l4[tid + 256] = s4[tid + 256];
    l4[tid + 384] = s4[tid + 384];
    if (tid < 64) l4[tid + 512] = s4[tid + 512];
    __syncthreads();

    // thread (i = cc offset 0..15, jp = g'-pair 0..7 -> j = 2jp, 2jp+1)
    const int i  = tid >> 3;
    const int jp = tid & 7;
    const float* __restrict__ vp = s + (i * 144 + jp * 18);

    f2 v[9];
#pragma unroll
    for (int t = 0; t < 9; ++t) v[t] = (f2){vp[t], vp[t + 9]};  // ds_read2_b32

    const float R3 = 1.0f/3.0f, R5 = 0.2f, R7 = 1.0f/7.0f, R9 = 1.0f/9.0f;
    const float NC = -0.5f * 1.44269504088896340736f;   // -0.5*log2(e)

    // ---- membership(x): nested sums ----
    const f2 s3 = v[3] + v[4] + v[5];
    const f2 s5 = s3 + v[2] + v[6];
    const f2 s7 = s5 + v[1] + v[7];
    const f2 s9 = s7 + v[0] + v[8];
    const f2 m3 = s3 * R3, m5 = s5 * R5, m7 = s7 * R7, m9 = s9 * R9;

    f2 kmm[5];
    kmm[0] = m7; kmm[1] = m5; kmm[2] = m3; kmm[3] = v[4]; kmm[4] = m9;

    const f2 v_avg = (m7 + m5 + m3 + v[4] + m9) * R5;

    // ---- omega = |x - v_avg|; var = membership(omega) + eps ----
    f2 w[9];
#pragma unroll
    for (int t = 0; t < 9; ++t) w[t] = abs2(v[t] - v_avg);

    const f2 t3 = w[3] + w[4] + w[5];
    const f2 t5 = t3 + w[2] + w[6];
    const f2 t7 = t5 + w[1] + w[7];
    const f2 t9 = t7 + w[0] + w[8];
    const f2 var4 = t9 * R9 + EPS;           // var[...,4] (m_only_var probe)

    f2 c[5];                                  // c_j = -0.5*log2e / var_j
    {
        const f2 a0 = t7 * R7 + EPS, a1 = t5 * R5 + EPS, a2 = t3 * R3 + EPS;
        c[0] = (f2){NC * rcp_f(a0.x), NC * rcp_f(a0.y)};
        c[1] = (f2){NC * rcp_f(a1.x), NC * rcp_f(a1.y)};
        c[2] = (f2){NC * rcp_f(a2.x), NC * rcp_f(a2.y)};
        c[3] = (f2){NC * rcp_f(w[4].x + EPS), NC * rcp_f(w[4].y + EPS)};
        c[4] = (f2){NC * rcp_f(var4.x), NC * rcp_f(var4.y)};
    }

    // ---- pi[jj][t] = 2^(c_jj * d^2); sum over jj all t, max over jj t!=4 ----
    // Exact: pi[3][4] = 1.0 bit-exactly; all pi <= 1 so max_pi[4] = 1.0 and
    // t=4 drops out of the thresh min-tree.
    f2 sum_pi[9], max_pi[9];
#pragma unroll
    for (int t = 0; t < 9; ++t) { sum_pi[t] = (f2)0.f; max_pi[t] = (f2)0.f; }

#pragma unroll
    for (int jj = 0; jj < 5; ++jj) {
        const f2 k  = kmm[jj];
        const f2 cj = c[jj];
#pragma unroll
        for (int t = 0; t < 9; ++t) {
            if (jj == 3 && t == 4) {          // d = v[4]-v[4] = +-0 exactly
                sum_pi[4] += 1.0f;            // same summation slot/order
                continue;
            }
            const f2 d  = v[t] - k;
            const f2 pi = exp2_2(cj * d * d);
            sum_pi[t] += pi;
            if (t != 4) max_pi[t] = max2(max_pi[t], pi);
        }
    }

    f2 thresh = min2(min2(max_pi[0], max_pi[1]), max_pi[2]);
    thresh = min2(thresh, max_pi[3]);
    thresh = min2(min2(thresh, max_pi[5]), max_pi[6]);
    thresh = min2(min2(thresh, max_pi[7]), max_pi[8]);

    // any_t(sum_pi[t]*0.2 > thresh)  <=>  max_t(sum_pi)*0.2 > thresh
    f2 ms = max2(max2(sum_pi[0], sum_pi[1]), sum_pi[2]);
    ms = max2(max2(ms, sum_pi[3]), sum_pi[4]);
    ms = max2(max2(ms, sum_pi[5]), sum_pi[6]);
    ms = max2(max2(ms, sum_pi[7]), sum_pi[8]);

    // weighted-average denoising; the 0.2 factor cancels in the ratio
    f2 sn = (f2)0.f, sd = (f2)0.f;
#pragma unroll
    for (int t = 0; t < 9; ++t) { sn += sum_pi[t] * v[t]; sd += sum_pi[t]; }
    const f2 den = (f2){sn.x * rcp_f(sd.x), sn.y * rcp_f(sd.y)};

    f2 res;
    res.x = ((ms.x * R5) > thresh.x) ? m9.x
           : ((var4.x < EPS) ? v_avg.x : den.x);
    res.y = ((ms.y * R5) > thresh.y) ? m9.y
           : ((var4.y < EPS) ? v_avg.y : den.y);

    const int cc = c8 * 16 + i;
    float* __restrict__ op =
        out + ((size_t)((b * 128 + r) * 128 + cc)) * 48 + kr * 16 + 2 * jp;
    *(f2*)op = res;                       // 8B-aligned dwordx2 store
}

extern "C" void kernel_launch(void* const* d_in, const int* in_sizes, int n_in,
                              void* d_out, int out_size, void* d_ws, size_t ws_size,
                              hipStream_t stream) {
    (void)in_sizes; (void)n_in; (void)d_ws; (void)ws_size; (void)out_size;
    const float* x = (const float*)d_in[0];
    float* out = (float*)d_out;
    const int blocks = 4 * 128 * 3 * 8;   // (b, r, kr, cc-octet) = 12288
    fuzzy_pool_kernel<<<blocks, 128, 0, stream>>>(x, out);
}